// Round 1
// baseline (78567.963 us; speedup 1.0000x reference)
//
#include <hip/hip_runtime.h>
#include <math.h>

// B=256 T=512 DIN=25 P=128 HID=256 3H=768 L=5 Q=0.15 EPS=1e-5
// Full-fp32. R5: kill the recur weight-stream. Old recur: 1 block per
// (sample,dir) re-read 768KB Whh from L2 EVERY step -> 5.7-8.3us/step floor
// (per-CU L2 port ~135GB/s), 64 steps/round -> ~530us rounds -> ~40ms.
// New recur: slice the 256 h-dims across P=8 partner blocks per
// (8-sample subgroup, dir). Each block keeps its 96x256 Whh slice
// REGISTER-RESIDENT (96 VGPR/thread, loaded once/launch), computes its 32
// h-dims for 8 samples per step (768 fma/thread ~0.64us), and exchanges
// 1KB h-slices with partners through device-scope (agent) atomics + an
// epoch-tagged flag per (set,step). Partner sets share identical trip
// counts (samples sorted, subgroup = 8 consecutive), recur blocks have the
// lowest blockIdx and all 256 fit co-resident (39KB LDS, ~150 VGPR), so
// the spin protocol cannot deadlock. GEMM role unchanged, co-resident.

#define CH 64

#define AT_LOAD_RLX(p)    __hip_atomic_load((p),  __ATOMIC_RELAXED, __HIP_MEMORY_SCOPE_AGENT)
#define AT_LOAD_ACQ(p)    __hip_atomic_load((p),  __ATOMIC_ACQUIRE, __HIP_MEMORY_SCOPE_AGENT)
#define AT_STORE_RLX(p,v) __hip_atomic_store((p),(v),__ATOMIC_RELAXED, __HIP_MEMORY_SCOPE_AGENT)
#define AT_STORE_REL(p,v) __hip_atomic_store((p),(v),__ATOMIC_RELEASE, __HIP_MEMORY_SCOPE_AGENT)

// ---------------- stable sort + per-group chunk counts ----------------
__global__ __launch_bounds__(256)
void sort_k(const int* __restrict__ len, int* __restrict__ perm,
            int* __restrict__ nchp, int Bg)
{
    __shared__ int ll[256];
    __shared__ int lp[256];
    const int i = threadIdx.x;
    const int li = len[i];
    ll[i] = li;
    __syncthreads();
    int rk = 0;
    for (int j = 0; j < 256; j++) {
        int lj = ll[j];
        rk += (lj < li || (lj == li && j < i)) ? 1 : 0;
    }
    lp[rk] = i;
    __syncthreads();
    perm[i] = lp[i];
    const int ngrp = 256 / Bg;
    if (i < ngrp) {
        int mx = ll[lp[i * Bg + Bg - 1]];      // ascending -> last rank is max
        int nch = (mx + 63) >> 6;
        nchp[i] = nch < 1 ? 1 : (nch > 8 ? 8 : nch);
    }
}

// ---------------- Whh transpose: whhT[l][d][k][c] ----------------
__global__ __launch_bounds__(256)
void prep_whhT_k(const float* __restrict__ Whh0, const float* __restrict__ Whh,
                 float* __restrict__ out)
{
    int id = blockIdx.x * 256 + threadIdx.x;   // exactly 1,966,080 threads
    int u = id / 196608, rr = id % 196608;     // u = l*2+d
    int k = rr / 768, c = rr % 768;
    int l = u >> 1, d = u & 1;
    out[id] = (l == 0) ? Whh0[(size_t)(d * 768 + c) * 256 + k]
                       : Whh[(size_t)(((l - 1) * 2 + d) * 768 + c) * 256 + k];
}

// ---------------- input projection: LN -> FC(25->128) -> GELU -> FC(128->128) --
__global__ __launch_bounds__(128)
void input_proj_k(const float* __restrict__ x, const int* __restrict__ lengths,
                  const int* __restrict__ perm,
                  const float* __restrict__ lng, const float* __restrict__ lnb,
                  const float* __restrict__ w1, const float* __restrict__ b1v,
                  const float* __restrict__ w2, const float* __restrict__ b2v,
                  float* __restrict__ out, int g0)
{
    const int btl = blockIdx.x;                // group-local (sl*512 + t)
    const int sl  = btl >> 9;
    const int t   = btl & 511;
    const int b   = perm[g0 + sl];
    if (t >= lengths[b]) return;               // masked rows never read downstream
    const int tid = threadIdx.x;
    __shared__ float xs[25];
    __shared__ float xn[25];
    __shared__ float hs[128];
    if (tid < 25) xs[tid] = x[((size_t)b * 512 + t) * 25 + tid];
    __syncthreads();
    if (tid < 25) {
        float mu = 0.f;
        #pragma unroll
        for (int k = 0; k < 25; k++) mu += xs[k];
        mu *= (1.f / 25.f);
        float var = 0.f;
        #pragma unroll
        for (int k = 0; k < 25; k++) { float dd = xs[k] - mu; var += dd * dd; }
        var *= (1.f / 25.f);
        float rstd = 1.f / sqrtf(var + 1e-5f);
        xn[tid] = (xs[tid] - mu) * rstd * lng[tid] + lnb[tid];
    }
    __syncthreads();
    float a = b1v[tid];
    #pragma unroll
    for (int k = 0; k < 25; k++) a = fmaf(xn[k], w1[k * 128 + tid], a);
    float ge = 0.5f * a * (1.f + erff(a * 0.70710678118654752440f));
    hs[tid] = ge;
    __syncthreads();
    float o = b2v[tid];
    #pragma unroll 8
    for (int k = 0; k < 128; k++) o = fmaf(hs[k], w2[k * 128 + tid], o);
    out[(size_t)btl * 128 + tid] = o;
}

// ---------------- fused round ----------------
// blocks [0, NR): recur role, NR = 2*Bg. Block = (dir d, subgroup sg of 8
//   consecutive sorted samples, h-dim slice sl of 32 dims). Whh slice in
//   VGPRs; per-step h exchange with 7 partner blocks via hx/flags.
// blocks [NR, NR+12*Bg): GEMM role (unchanged). 64Mx128N tile, K via LDS.
__global__ __launch_bounds__(256)
void round_k(const float* __restrict__ A, int K,
             const float* __restrict__ W,      // raw Wih layer slice [2][768][K]
             const float* __restrict__ bi,     // [2][768]
             const int* __restrict__ lengths, const int* __restrict__ perm,
             const int* __restrict__ nchp, int gidx, int g0, int Bg,
             float* __restrict__ xw_w,         // gemm out (round r)
             const float* __restrict__ xw_r,   // recur in (round r-1)
             const float* __restrict__ whhT,   // layer slice [2][256][768]
             const float* __restrict__ bhh,    // [2][768]
             float* __restrict__ Y,            // bout [Bg*512][512]
             int* __restrict__ hx,             // [2 par][2 d][Bg][256] f32-as-int
             int* __restrict__ flags,          // [2 d][Bg/8][8 sl][64 st]
             int NR, int r, int epoch)
{
    __shared__ float As[8][68];        // gemm: [k][m]
    __shared__ float Bs[8][132];       // gemm: [k][n]
    __shared__ float hsh[8][256];      // recur: full h for 8 samples
    __shared__ float gsb[8][8][96];    // recur: [kq][s][3*32] partial gh

    const int tid = threadIdx.x;
    const int nch = nchp[gidx];

    if ((int)blockIdx.x < NR) {
        // ================= recur role =================
        if (r == 0) return;
        const int d   = ((int)blockIdx.x >= Bg) ? 1 : 0;
        const int rr2 = (int)blockIdx.x - d * Bg;
        const int sg  = rr2 >> 3;              // sample subgroup (8 sorted samples)
        const int sl  = rr2 & 7;               // h-dim slice (32 dims)
        const int lo  = d ? (nch - r) * CH : (r - 1) * CH;
        if (lo < 0 || lo >= 512) return;
        const int mlsg = lengths[perm[g0 + sg * 8 + 7]];   // subgroup max (sorted)
        int nst = min(lo + CH, mlsg) - lo;
        if (nst <= 0) return;                  // identical across all 8 partners
        // first active round for this (d,sg): fwd starts at chunk 0; bwd starts
        // in the chunk containing mlsg-1 (prev higher chunk was inactive).
        const bool first = d ? (mlsg <= lo + CH) : (r == 1);

        const int kq = tid >> 5;               // phase1: K-slice 0..7 (32 wide)
        const int jj = tid & 31;               // phase1: dim within slice

        // register-resident Whh slice: w_g[k] = Whh[g*256+sl*32+jj][kq*32+k]
        const float* wb = whhT + (size_t)d * 196608 + (size_t)(kq * 32) * 768
                        + sl * 32 + jj;
        float w0[32], w1[32], w2[32];
        #pragma unroll
        for (int k = 0; k < 32; k++) {
            const float* wr = wb + (size_t)k * 768;
            w0[k] = wr[0];
            w1[k] = wr[256];
            w2[k] = wr[512];
        }

        const int s2 = tid >> 5;               // phase2: sample 0..7
        const int j2 = tid & 31;               // phase2: own h-dim within slice
        const int lens2 = lengths[perm[g0 + sg * 8 + s2]];
        const float bh0 = bhh[d * 768 +       sl * 32 + j2];
        const float bh1 = bhh[d * 768 + 256 + sl * 32 + j2];
        const float bh2 = bhh[d * 768 + 512 + sl * 32 + j2];
        const int sgN = Bg >> 3;
        int* flg = flags + (size_t)((d * sgN + sg) * 8) * 64;
        const int PS  = 2 * Bg * 256;          // parity-plane stride
        const int hxq = (d * Bg + sg * 8) * 256;
        float* hf = &hsh[0][0];

        if (first) {
            #pragma unroll
            for (int i = 0; i < 8; i++) hf[tid * 8 + i] = 0.f;
        } else {
            // previous round's last write (previous launch -> visible)
            const int pprev = d ? (lo + nst) : (lo - 1);
            const int par0  = pprev & 1;
            #pragma unroll
            for (int i = 0; i < 8; i++) {
                const int m = tid * 8 + i;
                hf[m] = __int_as_float(AT_LOAD_RLX(&hx[par0 * PS + hxq + m]));
            }
        }
        __syncthreads();

        const float* xwd = xw_r + (size_t)(d * Bg + sg * 8) * 64 * 768 + sl * 32 + j2;
        const int m0   = tid * 8;              // phase4: this thread's 8 dims
        const int dim0 = m0 & 255;
        int* fpoll = &flg[(dim0 >> 5) * 64];   // flag of the slice we re-read

        for (int st = 0; st < nst; st++) {
            const int p   = d ? (lo + nst - 1 - st) : (lo + st);
            const int row = p - lo;
            // xw prefetch (independent of h; hides L2 latency under phase1)
            const float* xr = xwd + (size_t)(s2 * 64 + row) * 768;
            const float xv0 = xr[0], xv1 = xr[256], xv2 = xr[512];

            // phase1: partial gh over this thread's K-slice, 3 gate rows
            #pragma unroll
            for (int s = 0; s < 8; s++) {
                float b0 = 0.f, b1 = 0.f, b2 = 0.f;
                #pragma unroll
                for (int k4 = 0; k4 < 8; k4++) {
                    const float4 h4 = *(const float4*)&hsh[s][kq * 32 + k4 * 4];
                    b0 = fmaf(h4.x, w0[k4 * 4 + 0], b0);
                    b0 = fmaf(h4.y, w0[k4 * 4 + 1], b0);
                    b0 = fmaf(h4.z, w0[k4 * 4 + 2], b0);
                    b0 = fmaf(h4.w, w0[k4 * 4 + 3], b0);
                    b1 = fmaf(h4.x, w1[k4 * 4 + 0], b1);
                    b1 = fmaf(h4.y, w1[k4 * 4 + 1], b1);
                    b1 = fmaf(h4.z, w1[k4 * 4 + 2], b1);
                    b1 = fmaf(h4.w, w1[k4 * 4 + 3], b1);
                    b2 = fmaf(h4.x, w2[k4 * 4 + 0], b2);
                    b2 = fmaf(h4.y, w2[k4 * 4 + 1], b2);
                    b2 = fmaf(h4.z, w2[k4 * 4 + 2], b2);
                    b2 = fmaf(h4.w, w2[k4 * 4 + 3], b2);
                }
                gsb[kq][s][jj]      = b0;
                gsb[kq][s][32 + jj] = b1;
                gsb[kq][s][64 + jj] = b2;
            }
            __syncthreads();                   // B1

            // phase2: gate update for (sample s2, h-dim sl*32+j2)
            float gr = bh0, gz = bh1, gn = bh2;
            #pragma unroll
            for (int q = 0; q < 8; q++) {
                gr += gsb[q][s2][j2];
                gz += gsb[q][s2][32 + j2];
                gn += gsb[q][s2][64 + j2];
            }
            const float rg = 1.f / (1.f + expf(-(xv0 + gr)));
            const float zg = 1.f / (1.f + expf(-(xv1 + gz)));
            const float ng = tanhf(xv2 + rg * gn);
            const float hv = hsh[s2][sl * 32 + j2];
            float hn = (1.f - zg) * ng + zg * hv;
            if (p >= lens2) hn = hv;           // hold state past sequence end
            const int par = p & 1;
            // publish own slice at the device-coherent point (cross-XCD safe)
            AT_STORE_RLX(&hx[par * PS + hxq + s2 * 256 + sl * 32 + j2],
                         __float_as_int(hn));
            if (p < lens2)
                Y[((size_t)((sg * 8 + s2) * 512 + p)) * 512 + d * 256 + sl * 32 + j2] = hn;
            __syncthreads();                   // B2: drains all hx stores (vmcnt 0)

            if (st == nst - 1) break;          // next round reads hx at launch edge
            if (tid == 0) AT_STORE_REL(&flg[sl * 64 + st], epoch);
            // phase4: spin on the producing slice's flag, refresh own 8 dims
            {
                int* f = fpoll + st;
                while (AT_LOAD_ACQ(f) != epoch) __builtin_amdgcn_s_sleep(2);
                #pragma unroll
                for (int i = 0; i < 8; i++)
                    hf[m0 + i] = __int_as_float(
                        AT_LOAD_RLX(&hx[par * PS + hxq + m0 + i]));
            }
            __syncthreads();                   // B3: hsh ready for next step
        }
    } else {
        // ================= GEMM role (unchanged) =================
        const int gid  = blockIdx.x - NR;
        const int nt   = gid % 6;
        const int rest = gid / 6;
        const int d    = (rest >= Bg) ? 1 : 0;
        const int s    = rest - d * Bg;
        const int lo   = d ? (nch - 1 - r) * 64 : r * 64;
        if (lo < 0 || lo >= 512) return;
        if (lengths[perm[g0 + s]] <= lo) return;   // chunk fully masked

        float acc[4][8] = {};
        const int tm = tid >> 4;                 // rows tm*4..+3
        const int tn = tid & 15;                 // cols {tn*4..+3, 64+tn*4..+3}
        const int arr = tid >> 2, ak = (tid & 3) * 2;
        const int bn = tid >> 1, bk = (tid & 1) * 4;

        const float* Ap = A + (size_t)(s * 512 + lo + arr) * K + ak;
        const float* Wp = W + ((size_t)d * 768 + nt * 128 + bn) * K + bk;

        for (int k0 = 0; k0 < K; k0 += 8) {
            float2 av = *(const float2*)(Ap + k0);
            float4 bv = *(const float4*)(Wp + k0);
            __syncthreads();
            As[ak][arr] = av.x; As[ak + 1][arr] = av.y;
            Bs[bk + 0][bn] = bv.x; Bs[bk + 1][bn] = bv.y;
            Bs[bk + 2][bn] = bv.z; Bs[bk + 3][bn] = bv.w;
            __syncthreads();
            #pragma unroll
            for (int kk = 0; kk < 8; kk++) {
                float4 a4 = *(const float4*)&As[kk][tm * 4];
                float4 b0v = *(const float4*)&Bs[kk][tn * 4];
                float4 b1v = *(const float4*)&Bs[kk][64 + tn * 4];
                float ar4[4] = {a4.x, a4.y, a4.z, a4.w};
                float br[8] = {b0v.x, b0v.y, b0v.z, b0v.w,
                               b1v.x, b1v.y, b1v.z, b1v.w};
                #pragma unroll
                for (int i = 0; i < 4; i++)
                    #pragma unroll
                    for (int j = 0; j < 8; j++)
                        acc[i][j] = fmaf(ar4[i], br[j], acc[i][j]);
            }
        }
        const int cb = d * 768 + nt * 128;
        float bv0[4], bv1[4];
        #pragma unroll
        for (int j = 0; j < 4; j++) {
            bv0[j] = bi[cb + tn * 4 + j];
            bv1[j] = bi[cb + 64 + tn * 4 + j];
        }
        #pragma unroll
        for (int i = 0; i < 4; i++) {
            const int row = tm * 4 + i;
            float* o = xw_w + (size_t)((d * Bg + s) * 64 + row) * 768 + nt * 128 + tn * 4;
            float4 c0 = make_float4(acc[i][0] + bv0[0], acc[i][1] + bv0[1],
                                    acc[i][2] + bv0[2], acc[i][3] + bv0[3]);
            float4 c1 = make_float4(acc[i][4] + bv1[0], acc[i][5] + bv1[1],
                                    acc[i][6] + bv1[2], acc[i][7] + bv1[3]);
            *(float4*)(o)      = c0;
            *(float4*)(o + 64) = c1;
        }
    }
}

// ---------------- top-Q pooling + classifier head ----------------
__global__ __launch_bounds__(256)
void pool_k(const float* __restrict__ H, const int* __restrict__ lengths,
            const int* __restrict__ perm,
            const float* __restrict__ Wc, const float* __restrict__ bcp,
            float* __restrict__ out, int g0)
{
    const int bl = blockIdx.x;
    const int b  = perm[g0 + bl];
    const int tid = threadIdx.x;
    __shared__ float sc[512];
    __shared__ int   sel[128];
    __shared__ int   nsel;
    __shared__ float red[256];
    const int len = lengths[b];
    const int k = max(1, (int)ceilf((float)len * 0.15f));   // jnp fp32 semantics
    if (tid == 0) nsel = 0;
    for (int t = tid; t < 512; t += 256) {
        float s;
        if (t < len) {
            const float* row = H + ((size_t)bl * 512 + t) * 512;
            float acc = 0.f;
            for (int j = 0; j < 512; j++) acc = fmaf(row[j], row[j], acc);
            s = sqrtf(acc);
        } else s = -1e9f;
        sc[t] = s;
    }
    __syncthreads();
    // stable top-k: include t iff (#strictly greater) + (#equal, smaller idx) < k
    for (int t = tid; t < 512; t += 256) {
        if (t < len) {
            const float s = sc[t];
            int cnt = 0;
            for (int u = 0; u < 512; u++) {
                float su = sc[u];
                cnt += (su > s || (su == s && u < t)) ? 1 : 0;
            }
            if (cnt < k) { int p = atomicAdd(&nsel, 1); sel[p] = t; }
        }
    }
    __syncthreads();
    const int ns = nsel;                       // == k
    float part = 0.f;
    for (int j = tid; j < 512; j += 256) {
        float acc = 0.f;
        for (int i = 0; i < ns; i++)
            acc += H[((size_t)bl * 512 + sel[i]) * 512 + j];
        part += (acc / (float)k) * Wc[j];
    }
    red[tid] = part;
    __syncthreads();
    for (int s2 = 128; s2 > 0; s2 >>= 1) {
        if (tid < s2) red[tid] += red[tid + s2];
        __syncthreads();
    }
    if (tid == 0) out[b] = red[0] + bcp[0];
}

// ---------------- host ----------------
static inline size_t alup(size_t x) { return (x + 255) & ~255ull; }

static size_t tier_bytes(int Bg)
{
    return 2 * alup((size_t)Bg * 512 * 512 * 4)        // H ping-pong
         + 2 * alup((size_t)Bg * 2 * 64 * 768 * 4)     // xw ping-pong
         + alup(1966080ull * 4)                        // whhT
         + alup((size_t)4 * Bg * 256 * 4)              // hx [2][2][Bg][256]
         + alup((size_t)2 * (Bg / 8) * 8 * 64 * 4)     // flags
         + alup(2048);                                 // perm + nch
}

extern "C" void kernel_launch(void* const* d_in, const int* in_sizes, int n_in,
                              void* d_out, int out_size, void* d_ws, size_t ws_size,
                              hipStream_t stream)
{
    const float* x    = (const float*)d_in[0];
    const int*   len  = (const int*)  d_in[1];
    const float* ln_g = (const float*)d_in[2];
    const float* ln_b = (const float*)d_in[3];
    const float* w1   = (const float*)d_in[4];
    const float* b1   = (const float*)d_in[5];
    const float* w2   = (const float*)d_in[6];
    const float* b2   = (const float*)d_in[7];
    const float* Wih0 = (const float*)d_in[8];
    const float* Whh0 = (const float*)d_in[9];
    const float* bih0 = (const float*)d_in[10];
    const float* bhh0 = (const float*)d_in[11];
    const float* Wih  = (const float*)d_in[12];
    const float* Whh  = (const float*)d_in[13];
    const float* bih  = (const float*)d_in[14];
    const float* bhh  = (const float*)d_in[15];
    const float* Wc   = (const float*)d_in[16];
    const float* bc   = (const float*)d_in[17];
    float* out = (float*)d_out;

    int Bg = 0;
    const int tiers[5] = {128, 64, 32, 16, 8};
    for (int i = 0; i < 5; i++)
        if (ws_size >= tier_bytes(tiers[i])) { Bg = tiers[i]; break; }
    if (Bg == 0) return;

    char* ws = (char*)d_ws;
    size_t off = 0;
    auto alloc = [&](size_t bytes) { size_t o = off; off += alup(bytes); return o; };
    float* h0    = (float*)(ws + alloc((size_t)Bg * 512 * 512 * 4));
    float* h1    = (float*)(ws + alloc((size_t)Bg * 512 * 512 * 4));
    float* xwA   = (float*)(ws + alloc((size_t)Bg * 2 * 64 * 768 * 4));
    float* xwB   = (float*)(ws + alloc((size_t)Bg * 2 * 64 * 768 * 4));
    float* whhT  = (float*)(ws + alloc(1966080ull * 4));
    int*   hx    = (int*)  (ws + alloc((size_t)4 * Bg * 256 * 4));
    const size_t flagBytes = (size_t)2 * (Bg / 8) * 8 * 64 * 4;
    int*   flags = (int*)  (ws + alloc(flagBytes));
    int*   perm  = (int*)  (ws + alloc(2048));
    int*   nchp  = perm + 256;
    float* xwbuf[2] = {xwA, xwB};

    // flags must be 0 at the start of EVERY replay (epochs restart per replay)
    hipMemsetAsync(flags, 0, flagBytes, stream);

    sort_k<<<1, 256, 0, stream>>>(len, perm, nchp, Bg);
    prep_whhT_k<<<7680, 256, 0, stream>>>(Whh0, Whh, whhT);

    const int NR = 2 * Bg;                 // recur blocks: (d, sg, slice)
    const int NG = 12 * Bg;                // gemm blocks (6 col tiles x 2 dirs x Bg)

    for (int g0 = 0; g0 < 256; g0 += Bg) {
        const int gidx = g0 / Bg;
        input_proj_k<<<Bg * 512, 128, 0, stream>>>(x, len, perm, ln_g, ln_b,
                                                   w1, b1, w2, b2, h0, g0);
        float* bin = h0;
        float* bout = h1;
        for (int l = 0; l < 5; l++) {
            const int K = (l == 0) ? 128 : 512;
            const float* Wl  = (l == 0) ? Wih0 : (Wih + (size_t)(l - 1) * 2 * 768 * 512);
            const float* bil = (l == 0) ? bih0 : (bih + (size_t)(l - 1) * 1536);
            const float* whl = whhT + (size_t)l * 393216;
            const float* bhl = (l == 0) ? bhh0 : (bhh + (size_t)(l - 1) * 1536);
            for (int r = 0; r <= 8; r++) {
                const int ep = (gidx * 5 + l) * 9 + r + 1;   // unique, nonzero
                round_k<<<NR + NG, 256, 0, stream>>>(
                    bin, K, Wl, bil, len, perm, nchp, gidx, g0, Bg,
                    xwbuf[r & 1], xwbuf[(r & 1) ^ 1],
                    whl, bhl, bout, hx, flags, NR, r, ep);
            }
            float* tmp = bin; bin = bout; bout = tmp;
        }
        pool_k<<<Bg, 256, 0, stream>>>(bin, len, perm, Wc, bc, out, g0);
    }
}

// Round 2
// 55906.421 us; speedup vs baseline: 1.4053x; 1.4053x over previous
//
#include <hip/hip_runtime.h>
#include <math.h>

// B=256 T=512 DIN=25 P=128 HID=256 3H=768 L=5 Q=0.15 EPS=1e-5
// Full-fp32. R6 = R5's cross-block recur exchange with the three measured
// defects fixed:
//  (a) R5's VGPR_Count=80 < 96 weight floats -> the "register-resident"
//      Whh slices were SPILLED to scratch (phase1 re-read 768 scratch words
//      per thread per step). Fix: __launch_bounds__(256,1) frees the
//      allocator + weights packed per-thread-contiguous (24 coalesced
//      float4 loads, natural 96-VGPR shape).
//  (b) SQ_LDS_BANK_CONFLICT 3.67M from hf[tid*8+i] refresh (8-way). Fix:
//      hf[i*256+tid] mapping (2-way = free; global side coalesced).
//  (c) 65k threads spinning agent-scope ACQUIRE on 256 flag words starved
//      the coherence fabric (30-40ms outlier dispatches). Fix: tid<8 poll
//      (1 lane per flag), barrier, then bulk load.
// Protocol (epoch flags, hx parity planes, partner sets = 8 consecutive
// sorted samples with identical trip counts) is unchanged from R5 (passed).

#define CH 64

#define AT_LOAD_RLX(p)    __hip_atomic_load((p),  __ATOMIC_RELAXED, __HIP_MEMORY_SCOPE_AGENT)
#define AT_LOAD_ACQ(p)    __hip_atomic_load((p),  __ATOMIC_ACQUIRE, __HIP_MEMORY_SCOPE_AGENT)
#define AT_STORE_RLX(p,v) __hip_atomic_store((p),(v),__ATOMIC_RELAXED, __HIP_MEMORY_SCOPE_AGENT)
#define AT_STORE_REL(p,v) __hip_atomic_store((p),(v),__ATOMIC_RELEASE, __HIP_MEMORY_SCOPE_AGENT)

// ---------------- stable sort + per-group chunk counts ----------------
__global__ __launch_bounds__(256)
void sort_k(const int* __restrict__ len, int* __restrict__ perm,
            int* __restrict__ nchp, int Bg)
{
    __shared__ int ll[256];
    __shared__ int lp[256];
    const int i = threadIdx.x;
    const int li = len[i];
    ll[i] = li;
    __syncthreads();
    int rk = 0;
    for (int j = 0; j < 256; j++) {
        int lj = ll[j];
        rk += (lj < li || (lj == li && j < i)) ? 1 : 0;
    }
    lp[rk] = i;
    __syncthreads();
    perm[i] = lp[i];
    const int ngrp = 256 / Bg;
    if (i < ngrp) {
        int mx = ll[lp[i * Bg + Bg - 1]];      // ascending -> last rank is max
        int nch = (mx + 63) >> 6;
        nchp[i] = nch < 1 ? 1 : (nch > 8 ? 8 : nch);
    }
}

// ---------------- Whh pack: per-thread-contiguous recur weight layout -----
// wpk[(l*2+d)][sl][t=kq*32+jj][g][k'] = Whh_raw[l][d][g*256+sl*32+jj][kq*32+k']
// Thread t of slice-block (d,sl) reads its 96 weights as 24 contiguous
// float4 at base + t*96. Layer stride stays 393216 floats.
__global__ __launch_bounds__(256)
void prep_whhT_k(const float* __restrict__ Whh0, const float* __restrict__ Whh,
                 float* __restrict__ out)
{
    int id = blockIdx.x * 256 + threadIdx.x;   // exactly 1,966,080 threads
    int k  = id & 31;
    int q  = id >> 5;                          // (((u*8+sl)*256+t)*3+g)
    int g  = q % 3;  q /= 3;
    int t  = q & 255; q >>= 8;
    int sl = q & 7;   q >>= 3;                 // q = u = l*2+d
    int l  = q >> 1, d = q & 1;
    int row = g * 256 + sl * 32 + (t & 31);
    int col = (t >> 5) * 32 + k;
    out[id] = (l == 0) ? Whh0[(size_t)(d * 768 + row) * 256 + col]
                       : Whh[(size_t)(((l - 1) * 2 + d) * 768 + row) * 256 + col];
}

// ---------------- input projection: LN -> FC(25->128) -> GELU -> FC(128->128) --
__global__ __launch_bounds__(128)
void input_proj_k(const float* __restrict__ x, const int* __restrict__ lengths,
                  const int* __restrict__ perm,
                  const float* __restrict__ lng, const float* __restrict__ lnb,
                  const float* __restrict__ w1, const float* __restrict__ b1v,
                  const float* __restrict__ w2, const float* __restrict__ b2v,
                  float* __restrict__ out, int g0)
{
    const int btl = blockIdx.x;                // group-local (sl*512 + t)
    const int sl  = btl >> 9;
    const int t   = btl & 511;
    const int b   = perm[g0 + sl];
    if (t >= lengths[b]) return;               // masked rows never read downstream
    const int tid = threadIdx.x;
    __shared__ float xs[25];
    __shared__ float xn[25];
    __shared__ float hs[128];
    if (tid < 25) xs[tid] = x[((size_t)b * 512 + t) * 25 + tid];
    __syncthreads();
    if (tid < 25) {
        float mu = 0.f;
        #pragma unroll
        for (int k = 0; k < 25; k++) mu += xs[k];
        mu *= (1.f / 25.f);
        float var = 0.f;
        #pragma unroll
        for (int k = 0; k < 25; k++) { float dd = xs[k] - mu; var += dd * dd; }
        var *= (1.f / 25.f);
        float rstd = 1.f / sqrtf(var + 1e-5f);
        xn[tid] = (xs[tid] - mu) * rstd * lng[tid] + lnb[tid];
    }
    __syncthreads();
    float a = b1v[tid];
    #pragma unroll
    for (int k = 0; k < 25; k++) a = fmaf(xn[k], w1[k * 128 + tid], a);
    float ge = 0.5f * a * (1.f + erff(a * 0.70710678118654752440f));
    hs[tid] = ge;
    __syncthreads();
    float o = b2v[tid];
    #pragma unroll 8
    for (int k = 0; k < 128; k++) o = fmaf(hs[k], w2[k * 128 + tid], o);
    out[(size_t)btl * 128 + tid] = o;
}

// ---------------- fused round ----------------
// blocks [0, NR): recur role, NR = 2*Bg. Block = (dir d, subgroup sg of 8
//   consecutive sorted samples, h-dim slice sl of 32 dims). 96 Whh weights
//   per thread in VGPRs (24 float4, contiguous); per-step h exchange with
//   7 partner blocks via hx parity planes + epoch flags (tid<8 poll).
// blocks [NR, NR+12*Bg): GEMM role (unchanged). 64Mx128N tile, K via LDS.
__global__ __launch_bounds__(256, 1)
void round_k(const float* __restrict__ A, int K,
             const float* __restrict__ W,      // raw Wih layer slice [2][768][K]
             const float* __restrict__ bi,     // [2][768]
             const int* __restrict__ lengths, const int* __restrict__ perm,
             const int* __restrict__ nchp, int gidx, int g0, int Bg,
             float* __restrict__ xw_w,         // gemm out (round r)
             const float* __restrict__ xw_r,   // recur in (round r-1)
             const float* __restrict__ whhT,   // packed layer slice (393216 f)
             const float* __restrict__ bhh,    // [2][768]
             float* __restrict__ Y,            // bout [Bg*512][512]
             int* __restrict__ hx,             // [2 par][2 d][Bg][256] f32-as-int
             int* __restrict__ flags,          // [2 d][Bg/8][8 sl][64 st]
             int NR, int r, int epoch)
{
    __shared__ float smem[8192];               // 32KB union of both roles

    const int tid = threadIdx.x;
    const int nch = nchp[gidx];

    if ((int)blockIdx.x < NR) {
        // ================= recur role =================
        if (r == 0) return;
        const int d   = ((int)blockIdx.x >= Bg) ? 1 : 0;
        const int rr2 = (int)blockIdx.x - d * Bg;
        const int sg  = rr2 >> 3;              // sample subgroup (8 sorted samples)
        const int sl  = rr2 & 7;               // h-dim slice (32 dims)
        const int lo  = d ? (nch - r) * CH : (r - 1) * CH;
        if (lo < 0 || lo >= 512) return;
        const int mlsg = lengths[perm[g0 + sg * 8 + 7]];   // subgroup max (sorted)
        int nst = min(lo + CH, mlsg) - lo;
        if (nst <= 0) return;                  // identical across all 8 partners
        const bool first = d ? (mlsg <= lo + CH) : (r == 1);

        float* hf   = smem;                    // [8][256] h for 8 samples
        float* gsbp = smem + 2048;             // [8 kq][8 s][96] partials

        const int kq = tid >> 5;               // K-slice 0..7 (32 wide)
        const int jj = tid & 31;               // dim within slice

        // 96 weights, contiguous per thread: 24 coalesced float4 loads
        const float* wb = whhT + ((size_t)(d * 8 + sl) * 256 + tid) * 96;
        float4 w[3][8];
        #pragma unroll
        for (int g = 0; g < 3; g++)
            #pragma unroll
            for (int k4 = 0; k4 < 8; k4++)
                w[g][k4] = *(const float4*)(wb + g * 32 + k4 * 4);

        const int s2 = tid >> 5;               // phase2: sample 0..7
        const int j2 = tid & 31;               // phase2: own h-dim within slice
        const int lens2 = lengths[perm[g0 + sg * 8 + s2]];
        const float bh0 = bhh[d * 768 +       sl * 32 + j2];
        const float bh1 = bhh[d * 768 + 256 + sl * 32 + j2];
        const float bh2 = bhh[d * 768 + 512 + sl * 32 + j2];
        const int sgN = Bg >> 3;
        int* flg = flags + (size_t)((d * sgN + sg) * 8) * 64;
        const int PS  = 2 * Bg * 256;          // parity-plane stride
        const int hxq = (d * Bg + sg * 8) * 256;

        if (first) {
            #pragma unroll
            for (int i = 0; i < 8; i++) hf[i * 256 + tid] = 0.f;
        } else {
            const int pprev = d ? (lo + nst) : (lo - 1);
            const int par0  = pprev & 1;
            const int* src = hx + par0 * PS + hxq;
            #pragma unroll
            for (int i = 0; i < 8; i++)
                hf[i * 256 + tid] = __int_as_float(AT_LOAD_RLX(src + i * 256 + tid));
        }
        __syncthreads();

        const float* xwd = xw_r + (size_t)(d * Bg + sg * 8) * 64 * 768 + sl * 32 + j2;

        for (int st = 0; st < nst; st++) {
            const int p   = d ? (lo + nst - 1 - st) : (lo + st);
            const int row = p - lo;
            // xw prefetch (independent of h; hides L2 latency under phase1)
            const float* xr = xwd + (size_t)(s2 * 64 + row) * 768;
            const float xv0 = xr[0], xv1 = xr[256], xv2 = xr[512];

            // phase1: partial gh over this thread's K-slice, 3 gate rows
            #pragma unroll
            for (int s = 0; s < 8; s++) {
                float b0 = 0.f, b1 = 0.f, b2 = 0.f;
                #pragma unroll
                for (int k4 = 0; k4 < 8; k4++) {
                    const float4 h4 = *(const float4*)&hf[s * 256 + kq * 32 + k4 * 4];
                    b0 = fmaf(h4.x, w[0][k4].x, b0);
                    b0 = fmaf(h4.y, w[0][k4].y, b0);
                    b0 = fmaf(h4.z, w[0][k4].z, b0);
                    b0 = fmaf(h4.w, w[0][k4].w, b0);
                    b1 = fmaf(h4.x, w[1][k4].x, b1);
                    b1 = fmaf(h4.y, w[1][k4].y, b1);
                    b1 = fmaf(h4.z, w[1][k4].z, b1);
                    b1 = fmaf(h4.w, w[1][k4].w, b1);
                    b2 = fmaf(h4.x, w[2][k4].x, b2);
                    b2 = fmaf(h4.y, w[2][k4].y, b2);
                    b2 = fmaf(h4.z, w[2][k4].z, b2);
                    b2 = fmaf(h4.w, w[2][k4].w, b2);
                }
                gsbp[(kq * 8 + s) * 96 + jj]      = b0;
                gsbp[(kq * 8 + s) * 96 + 32 + jj] = b1;
                gsbp[(kq * 8 + s) * 96 + 64 + jj] = b2;
            }
            __syncthreads();                   // B1

            // phase2: gate update for (sample s2, h-dim sl*32+j2)
            float gr = bh0, gz = bh1, gn = bh2;
            #pragma unroll
            for (int q = 0; q < 8; q++) {
                gr += gsbp[(q * 8 + s2) * 96 + j2];
                gz += gsbp[(q * 8 + s2) * 96 + 32 + j2];
                gn += gsbp[(q * 8 + s2) * 96 + 64 + j2];
            }
            const float rg = 1.f / (1.f + expf(-(xv0 + gr)));
            const float zg = 1.f / (1.f + expf(-(xv1 + gz)));
            const float ng = tanhf(xv2 + rg * gn);
            const float hv = hf[s2 * 256 + sl * 32 + j2];
            float hn = (1.f - zg) * ng + zg * hv;
            if (p >= lens2) hn = hv;           // hold state past sequence end
            const int par = p & 1;
            AT_STORE_RLX(&hx[par * PS + hxq + s2 * 256 + sl * 32 + j2],
                         __float_as_int(hn));
            if (p < lens2)
                Y[((size_t)((sg * 8 + s2) * 512 + p)) * 512 + d * 256 + sl * 32 + j2] = hn;
            __syncthreads();                   // B2: drains hx stores (vmcnt 0)

            if (st == nst - 1) break;          // next round reads hx at launch edge
            if (tid == 0) AT_STORE_REL(&flg[sl * 64 + st], epoch);
            if (tid < 8) {                     // 1 lane per producing slice
                int* f = &flg[tid * 64 + st];
                while (AT_LOAD_ACQ(f) != epoch) __builtin_amdgcn_s_sleep(2);
            }
            __syncthreads();                   // all 8 flags confirmed
            {
                const int* src = hx + par * PS + hxq;
                #pragma unroll
                for (int i = 0; i < 8; i++)
                    hf[i * 256 + tid] = __int_as_float(
                        AT_LOAD_RLX(src + i * 256 + tid));
            }
            __syncthreads();                   // B3: hsh ready for next step
        }
    } else {
        // ================= GEMM role (unchanged) =================
        float (*As)[68]  = (float(*)[68])smem;
        float (*Bs)[132] = (float(*)[132])(smem + 544);

        const int gid  = blockIdx.x - NR;
        const int nt   = gid % 6;
        const int rest = gid / 6;
        const int d    = (rest >= Bg) ? 1 : 0;
        const int s    = rest - d * Bg;
        const int lo   = d ? (nch - 1 - r) * 64 : r * 64;
        if (lo < 0 || lo >= 512) return;
        if (lengths[perm[g0 + s]] <= lo) return;   // chunk fully masked

        float acc[4][8] = {};
        const int tm = tid >> 4;                 // rows tm*4..+3
        const int tn = tid & 15;                 // cols {tn*4..+3, 64+tn*4..+3}
        const int arr = tid >> 2, ak = (tid & 3) * 2;
        const int bn = tid >> 1, bk = (tid & 1) * 4;

        const float* Ap = A + (size_t)(s * 512 + lo + arr) * K + ak;
        const float* Wp = W + ((size_t)d * 768 + nt * 128 + bn) * K + bk;

        for (int k0 = 0; k0 < K; k0 += 8) {
            float2 av = *(const float2*)(Ap + k0);
            float4 bv = *(const float4*)(Wp + k0);
            __syncthreads();
            As[ak][arr] = av.x; As[ak + 1][arr] = av.y;
            Bs[bk + 0][bn] = bv.x; Bs[bk + 1][bn] = bv.y;
            Bs[bk + 2][bn] = bv.z; Bs[bk + 3][bn] = bv.w;
            __syncthreads();
            #pragma unroll
            for (int kk = 0; kk < 8; kk++) {
                float4 a4 = *(const float4*)&As[kk][tm * 4];
                float4 b0v = *(const float4*)&Bs[kk][tn * 4];
                float4 b1v = *(const float4*)&Bs[kk][64 + tn * 4];
                float ar4[4] = {a4.x, a4.y, a4.z, a4.w};
                float br[8] = {b0v.x, b0v.y, b0v.z, b0v.w,
                               b1v.x, b1v.y, b1v.z, b1v.w};
                #pragma unroll
                for (int i = 0; i < 4; i++)
                    #pragma unroll
                    for (int j = 0; j < 8; j++)
                        acc[i][j] = fmaf(ar4[i], br[j], acc[i][j]);
            }
        }
        const int cb = d * 768 + nt * 128;
        float bv0[4], bv1[4];
        #pragma unroll
        for (int j = 0; j < 4; j++) {
            bv0[j] = bi[cb + tn * 4 + j];
            bv1[j] = bi[cb + 64 + tn * 4 + j];
        }
        #pragma unroll
        for (int i = 0; i < 4; i++) {
            const int row = tm * 4 + i;
            float* o = xw_w + (size_t)((d * Bg + s) * 64 + row) * 768 + nt * 128 + tn * 4;
            float4 c0 = make_float4(acc[i][0] + bv0[0], acc[i][1] + bv0[1],
                                    acc[i][2] + bv0[2], acc[i][3] + bv0[3]);
            float4 c1 = make_float4(acc[i][4] + bv1[0], acc[i][5] + bv1[1],
                                    acc[i][6] + bv1[2], acc[i][7] + bv1[3]);
            *(float4*)(o)      = c0;
            *(float4*)(o + 64) = c1;
        }
    }
}

// ---------------- top-Q pooling + classifier head ----------------
__global__ __launch_bounds__(256)
void pool_k(const float* __restrict__ H, const int* __restrict__ lengths,
            const int* __restrict__ perm,
            const float* __restrict__ Wc, const float* __restrict__ bcp,
            float* __restrict__ out, int g0)
{
    const int bl = blockIdx.x;
    const int b  = perm[g0 + bl];
    const int tid = threadIdx.x;
    __shared__ float sc[512];
    __shared__ int   sel[128];
    __shared__ int   nsel;
    __shared__ float red[256];
    const int len = lengths[b];
    const int k = max(1, (int)ceilf((float)len * 0.15f));   // jnp fp32 semantics
    if (tid == 0) nsel = 0;
    for (int t = tid; t < 512; t += 256) {
        float s;
        if (t < len) {
            const float* row = H + ((size_t)bl * 512 + t) * 512;
            float acc = 0.f;
            for (int j = 0; j < 512; j++) acc = fmaf(row[j], row[j], acc);
            s = sqrtf(acc);
        } else s = -1e9f;
        sc[t] = s;
    }
    __syncthreads();
    // stable top-k: include t iff (#strictly greater) + (#equal, smaller idx) < k
    for (int t = tid; t < 512; t += 256) {
        if (t < len) {
            const float s = sc[t];
            int cnt = 0;
            for (int u = 0; u < 512; u++) {
                float su = sc[u];
                cnt += (su > s || (su == s && u < t)) ? 1 : 0;
            }
            if (cnt < k) { int p = atomicAdd(&nsel, 1); sel[p] = t; }
        }
    }
    __syncthreads();
    const int ns = nsel;                       // == k
    float part = 0.f;
    for (int j = tid; j < 512; j += 256) {
        float acc = 0.f;
        for (int i = 0; i < ns; i++)
            acc += H[((size_t)bl * 512 + sel[i]) * 512 + j];
        part += (acc / (float)k) * Wc[j];
    }
    red[tid] = part;
    __syncthreads();
    for (int s2 = 128; s2 > 0; s2 >>= 1) {
        if (tid < s2) red[tid] += red[tid + s2];
        __syncthreads();
    }
    if (tid == 0) out[b] = red[0] + bcp[0];
}

// ---------------- host ----------------
static inline size_t alup(size_t x) { return (x + 255) & ~255ull; }

static size_t tier_bytes(int Bg)
{
    return 2 * alup((size_t)Bg * 512 * 512 * 4)        // H ping-pong
         + 2 * alup((size_t)Bg * 2 * 64 * 768 * 4)     // xw ping-pong
         + alup(1966080ull * 4)                        // packed Whh
         + alup((size_t)4 * Bg * 256 * 4)              // hx [2][2][Bg][256]
         + alup((size_t)2 * (Bg / 8) * 8 * 64 * 4)     // flags
         + alup(2048);                                 // perm + nch
}

extern "C" void kernel_launch(void* const* d_in, const int* in_sizes, int n_in,
                              void* d_out, int out_size, void* d_ws, size_t ws_size,
                              hipStream_t stream)
{
    const float* x    = (const float*)d_in[0];
    const int*   len  = (const int*)  d_in[1];
    const float* ln_g = (const float*)d_in[2];
    const float* ln_b = (const float*)d_in[3];
    const float* w1   = (const float*)d_in[4];
    const float* b1   = (const float*)d_in[5];
    const float* w2   = (const float*)d_in[6];
    const float* b2   = (const float*)d_in[7];
    const float* Wih0 = (const float*)d_in[8];
    const float* Whh0 = (const float*)d_in[9];
    const float* bih0 = (const float*)d_in[10];
    const float* bhh0 = (const float*)d_in[11];
    const float* Wih  = (const float*)d_in[12];
    const float* Whh  = (const float*)d_in[13];
    const float* bih  = (const float*)d_in[14];
    const float* bhh  = (const float*)d_in[15];
    const float* Wc   = (const float*)d_in[16];
    const float* bc   = (const float*)d_in[17];
    float* out = (float*)d_out;

    int Bg = 0;
    const int tiers[5] = {128, 64, 32, 16, 8};
    for (int i = 0; i < 5; i++)
        if (ws_size >= tier_bytes(tiers[i])) { Bg = tiers[i]; break; }
    if (Bg == 0) return;

    char* ws = (char*)d_ws;
    size_t off = 0;
    auto alloc = [&](size_t bytes) { size_t o = off; off += alup(bytes); return o; };
    float* h0    = (float*)(ws + alloc((size_t)Bg * 512 * 512 * 4));
    float* h1    = (float*)(ws + alloc((size_t)Bg * 512 * 512 * 4));
    float* xwA   = (float*)(ws + alloc((size_t)Bg * 2 * 64 * 768 * 4));
    float* xwB   = (float*)(ws + alloc((size_t)Bg * 2 * 64 * 768 * 4));
    float* whhT  = (float*)(ws + alloc(1966080ull * 4));
    int*   hx    = (int*)  (ws + alloc((size_t)4 * Bg * 256 * 4));
    const size_t flagBytes = (size_t)2 * (Bg / 8) * 8 * 64 * 4;
    int*   flags = (int*)  (ws + alloc(flagBytes));
    int*   perm  = (int*)  (ws + alloc(2048));
    int*   nchp  = perm + 256;
    float* xwbuf[2] = {xwA, xwB};

    // flags must be 0 at the start of EVERY replay (epochs restart per replay)
    hipMemsetAsync(flags, 0, flagBytes, stream);

    sort_k<<<1, 256, 0, stream>>>(len, perm, nchp, Bg);
    prep_whhT_k<<<7680, 256, 0, stream>>>(Whh0, Whh, whhT);

    const int NR = 2 * Bg;                 // recur blocks: (d, sg, slice)
    const int NG = 12 * Bg;                // gemm blocks (6 col tiles x 2 dirs x Bg)

    for (int g0 = 0; g0 < 256; g0 += Bg) {
        const int gidx = g0 / Bg;
        input_proj_k<<<Bg * 512, 128, 0, stream>>>(x, len, perm, ln_g, ln_b,
                                                   w1, b1, w2, b2, h0, g0);
        float* bin = h0;
        float* bout = h1;
        for (int l = 0; l < 5; l++) {
            const int K = (l == 0) ? 128 : 512;
            const float* Wl  = (l == 0) ? Wih0 : (Wih + (size_t)(l - 1) * 2 * 768 * 512);
            const float* bil = (l == 0) ? bih0 : (bih + (size_t)(l - 1) * 1536);
            const float* whl = whhT + (size_t)l * 393216;
            const float* bhl = (l == 0) ? bhh0 : (bhh + (size_t)(l - 1) * 1536);
            for (int r = 0; r <= 8; r++) {
                const int ep = (gidx * 5 + l) * 9 + r + 1;   // unique, nonzero
                round_k<<<NR + NG, 256, 0, stream>>>(
                    bin, K, Wl, bil, len, perm, nchp, gidx, g0, Bg,
                    xwbuf[r & 1], xwbuf[(r & 1) ^ 1],
                    whl, bhl, bout, hx, flags, NR, r, ep);
            }
            float* tmp = bin; bin = bout; bout = tmp;
        }
        pool_k<<<Bg, 256, 0, stream>>>(bin, len, perm, Wc, bc, out, g0);
    }
}